// Round 10
// baseline (187.541 us; speedup 1.0000x reference)
//
#include <hip/hip_runtime.h>
#include <math.h>

#define BATCH 2
#define CH    192
#define NPTS  8192
#define KNN   9

#define NT     64      // rows per normalize block
#define TLIST  5       // per-bucket candidate list depth
#define NTILE  512     // 16-wide row/col tiles per batch
#define KSTEP  6       // 192 / 32
#define CSPLIT 8       // column splits (phase 1)
#define CT     2       // col tiles staged per iteration
#define NITER  ((NTILE / CSPLIT) / CT)   // 32
#define NCANDP 640     // packed candidates per row (8 cs * 16 bins * 5)
#define P2ROWS 4       // phase-2 rows per block (1 per wave)

typedef __attribute__((ext_vector_type(8))) short  bf16x8;
typedef __attribute__((ext_vector_type(8))) unsigned short u16x8;
typedef __attribute__((ext_vector_type(4))) float  f32x4;

static __device__ __forceinline__ unsigned short f2bf(float f) {
    unsigned u = __float_as_uint(f);
    u += 0x7fffu + ((u >> 16) & 1u);          // round-to-nearest-even
    return (unsigned short)(u >> 16);
}
static __device__ __forceinline__ bf16x8 negbf(bf16x8 v) {
    bf16x8 r;
    #pragma unroll
    for (int e = 0; e < 8; ++e) r[e] = (short)(v[e] ^ (short)0x8000);
    return r;
}
static __device__ __forceinline__ unsigned umax2(unsigned a, unsigned b) {
    return a > b ? a : b;
}

// ---------------------------------------------------------------------------
// Kernel A: norms + layouts (unchanged — passing since R9).
//  pk [B][tile(512)][ks(6)][lane(64)*8] bf16 hi-only MFMA-frag layout
//  x_rm [B][N][C] f32 raw; rdnd/ssd f64 per point.
// ---------------------------------------------------------------------------
__global__ __launch_bounds__(256) void knn_normalize(
    const float* __restrict__ x,
    unsigned short* __restrict__ pk, float* __restrict__ x_rm,
    double* __restrict__ rdnd, double* __restrict__ ssd)
{
    __shared__ float  tile[CH][NT + 1];
    __shared__ double rdn_sh[NT];

    const int b   = blockIdx.x >> 7;
    const int rb  = blockIdx.x & 127;
    const int n0  = rb << 6;
    const int tid = threadIdx.x;
    const float* xb = x + (size_t)b * CH * NPTS;

    #pragma unroll
    for (int i = 0; i < (CH * NT) / 256; ++i) {
        int flat = tid + i * 256;
        int c = flat >> 6, j = flat & 63;
        tile[c][j] = xb[(size_t)c * NPTS + n0 + j];
    }
    __syncthreads();

    // 4 threads per point: quarter q covers dims q*48..q*48+47
    {
        const int j = tid >> 2, q = tid & 3;
        double ss = 0.0;
        #pragma unroll 8
        for (int c = 0; c < 48; ++c) {
            double v = (double)tile[q * 48 + c][j];
            ss = fma(v, v, ss);
        }
        ss += __shfl_xor(ss, 1, 64);
        ss += __shfl_xor(ss, 2, 64);
        if (q == 0) {
            double dn = sqrt(ss);
            if (dn < 1e-12) dn = 1e-12;
            double rdn = 1.0 / dn;
            rdn_sh[j] = rdn;
            rdnd[b * NPTS + n0 + j] = rdn;
            ssd [b * NPTS + n0 + j] = ss;
        }
    }
    __syncthreads();

    // packed MFMA-frag bf16 hi (4 row-tiles * 6 ksteps = 24 frags/block)
    #pragma unroll
    for (int i = 0; i < 6; ++i) {
        int pid  = tid + i * 256;
        int frag = pid >> 6;
        int lane = pid & 63;
        int tl   = frag / KSTEP;
        int ks   = frag - tl * KSTEP;
        int rl   = (tl << 4) + (lane & 15);
        int kb   = (ks << 5) + ((lane >> 4) << 3);
        double rdn = rdn_sh[rl];
        u16x8 hv;
        #pragma unroll
        for (int e = 0; e < 8; ++e) {
            float v = (float)((double)tile[kb + e][rl] * rdn);
            hv[e] = f2bf(v);
        }
        size_t base = ((size_t)((b * NTILE + (rb << 2) + tl) * KSTEP + ks)) * 512
                      + ((size_t)lane << 3);
        *(u16x8*)(pk + base) = hv;
    }

    #pragma unroll
    for (int i = 0; i < (CH * NT) / 256; ++i) {
        int flat = tid + i * 256;
        int j = flat / CH, c = flat - j * CH;
        x_rm[(size_t)(b * NPTS + n0 + j) * CH + c] = tile[c][j];
    }
}

// ---------------------------------------------------------------------------
// Phase 1 v7: as R9, but a_hi fragments are PINNED to the AGPR class via
// empty inline-asm "+a" constraints. gfx950 MFMA reads A directly from
// AGPRs (ISA §10), so a_hi+acc occupy the accum half of the unified RF and
// the arch-VGPR half is free for lst/wmax -> selection runs without
// v_accvgpr_read/write ping-pong (R8/R9: ~60k cyc/SIMD of moves).
// ---------------------------------------------------------------------------
__global__ __attribute__((amdgpu_flat_work_group_size(256, 256),
                          amdgpu_waves_per_eu(4, 4)))
void knn_phase1(
    const unsigned short* __restrict__ pk,
    unsigned* __restrict__ cand_p)
{
    __shared__ unsigned short ldsB[2][CT * KSTEP * 512];   // 2 x 12288 B

    const int bid  = blockIdx.x;          // 1024
    const int b    = bid >> 9;
    const int r9   = bid & 511;
    const int rb   = r9 >> 3;             // row block (128 rows), 0..63
    const int cs   = r9 & 7;              // column split, 0..7
    const int tid  = threadIdx.x;
    const int wave = tid >> 6;
    const int lane = tid & 63;
    const unsigned short* pkb = pk + (size_t)b * (NTILE * KSTEP * 512);
    const int ct0 = cs * (NTILE / CSPLIT);       // 64 tiles per split

    // A fragments: 2 row tiles per wave, NEGATED (for acc = 4 - inner)
    bf16x8 a_hi[2][KSTEP];
    #pragma unroll
    for (int ri = 0; ri < 2; ++ri) {
        const int rt = rb * 8 + wave * 2 + ri;
        #pragma unroll
        for (int ks = 0; ks < KSTEP; ++ks) {
            const unsigned short* p = pkb + ((size_t)(rt * KSTEP + ks)) * 512 + (lane << 3);
            a_hi[ri][ks] = negbf(*(const bf16x8*)p);
        }
    }
    // pin MFMA-only A fragments into the AGPR register class
    #pragma unroll
    for (int ri = 0; ri < 2; ++ri)
        #pragma unroll
        for (int ks = 0; ks < KSTEP; ++ks)
            asm volatile("" : "+a"(a_hi[ri][ks]));

    // packed lists; sentinels above all real keys (real < 0x40C00000)
    unsigned lst[8][TLIST];
    unsigned wmax[8];
    #pragma unroll
    for (int s = 0; s < 8; ++s) {
        #pragma unroll
        for (int t = 0; t < TLIST; ++t) lst[s][t] = 0xFFFFFF00u | t;
        wmax[s] = 0xFFFFFF00u | (TLIST - 1);
    }

    // prologue stage of buffer 0 (12 KB = 3 x 256 x 16B)
    {
        const char* g = (const char*)(pkb + (size_t)ct0 * (KSTEP * 512));
        #pragma unroll
        for (int k = 0; k < 3; ++k) {
            int off = (k * 256 + tid) * 16;
            __builtin_amdgcn_global_load_lds(
                (const __attribute__((address_space(1))) unsigned int*)(g + off),
                (__attribute__((address_space(3))) unsigned int*)((char*)&ldsB[0][0] + off),
                16, 0, 0);
        }
    }
    __syncthreads();

    for (int it = 0; it < NITER; ++it) {
        const int cur = it & 1;
        if (it + 1 < NITER) {
            const char* g = (const char*)(pkb + (size_t)(ct0 + (it + 1) * CT) * (KSTEP * 512));
            #pragma unroll
            for (int k = 0; k < 3; ++k) {
                int off = (k * 256 + tid) * 16;
                __builtin_amdgcn_global_load_lds(
                    (const __attribute__((address_space(1))) unsigned int*)(g + off),
                    (__attribute__((address_space(3))) unsigned int*)((char*)&ldsB[cur ^ 1][0] + off),
                    16, 0, 0);
            }
        }

        f32x4 acc[2][CT];
        #pragma unroll
        for (int ri = 0; ri < 2; ++ri)
            #pragma unroll
            for (int j = 0; j < CT; ++j) acc[ri][j] = (f32x4){4.f, 4.f, 4.f, 4.f};

        #pragma unroll
        for (int ks = 0; ks < KSTEP; ++ks) {
            #pragma unroll
            for (int j = 0; j < CT; ++j) {
                bf16x8 bh = *(const bf16x8*)&ldsB[cur][(j * KSTEP + ks) * 512 + (lane << 3)];
                acc[0][j] = __builtin_amdgcn_mfma_f32_16x16x32_bf16(a_hi[0][ks], bh, acc[0][j], 0, 0, 0);
                acc[1][j] = __builtin_amdgcn_mfma_f32_16x16x32_bf16(a_hi[1][ks], bh, acc[1][j], 0, 0, 0);
            }
        }

        // selection: key = 4 - inner (positive) -> p = (bits & ~0x7F) | tile
        #pragma unroll
        for (int ri = 0; ri < 2; ++ri)
            #pragma unroll
            for (int j = 0; j < CT; ++j) {
                const unsigned ctl = (unsigned)(it * CT + j);   // 0..63
                #pragma unroll
                for (int s = 0; s < 4; ++s) {
                    const int sl = ri * 4 + s;
                    unsigned p = (__float_as_uint(acc[ri][j][s]) & 0xFFFFFF80u) | ctl;
                    const unsigned wm = wmax[sl];
                    if (p < wm) {
                        #pragma unroll
                        for (int t = 0; t < TLIST; ++t)
                            lst[sl][t] = (lst[sl][t] == wm) ? p : lst[sl][t];
                        unsigned m0 = umax2(umax2(lst[sl][0], lst[sl][1]), lst[sl][2]);
                        wmax[sl] = umax2(umax2(m0, lst[sl][3]), lst[sl][4]);
                    }
                }
            }
        __syncthreads();
    }

    // write candidates: [B*N][640], slot = cs*80 + bin*5 + t
    const int bin = lane & 15;
    #pragma unroll
    for (int ri = 0; ri < 2; ++ri) {
        const int rt = rb * 8 + wave * 2 + ri;
        #pragma unroll
        for (int s = 0; s < 4; ++s) {
            int row = (rt << 4) + ((lane >> 4) << 2) + s;
            size_t base = (size_t)(b * NPTS + row) * NCANDP + cs * 80 + bin * 5;
            #pragma unroll
            for (int t = 0; t < TLIST; ++t)
                cand_p[base + t] = lst[ri * 4 + s][t];
        }
    }
}

// ---------------------------------------------------------------------------
// Phase 2 (unchanged from R8 — passing): 1 row per wave, 4 rows/block.
//  (a) per-lane 10 packed cands (2 buckets of 5), insertion-sort, 16-round
//      wave-min extraction
//  (b) f64 re-rank: lane=(cand,quarter), float4 gathers, 2-shfl reduce
//  (c) lane-0 serial 9-of-16 by (f64 key, idx)
// ---------------------------------------------------------------------------
__global__ __launch_bounds__(256) void knn_phase2(
    const float* __restrict__ x_rm,
    const double* __restrict__ rdnd, const double* __restrict__ ssd,
    const unsigned* __restrict__ cand_p,
    int* __restrict__ out)
{
    __shared__ double xc[P2ROWS][CH];     // 6144 B
    __shared__ int    sel[P2ROWS][16];
    __shared__ double dks[P2ROWS][16];

    const int bi   = blockIdx.x;          // 4096
    const int b    = bi >> 11;
    const int r0   = (bi & 2047) << 2;
    const int tid  = threadIdx.x;
    const int wave = tid >> 6;
    const int lane = tid & 63;
    const int bN   = b * NPTS;

    for (int i = tid; i < P2ROWS * CH; i += 256) {
        int r = i / CH, c = i - r * CH;
        xc[r][c] = (double)x_rm[(size_t)(bN + r0 + r) * CH + c] * rdnd[bN + r0 + r];
    }
    __syncthreads();

    const int row = r0 + wave;

    // (a) lane's 10 slots: cs = lane>>3; bins (lane&7)*2 + u/5
    unsigned long long qq[10];
    {
        const unsigned* cp = cand_p + (size_t)(bN + row) * NCANDP + lane * 10;
        const int csq = lane >> 3;
        const int bin0 = (lane & 7) << 1;
        #pragma unroll
        for (int u = 0; u < 10; ++u) {
            unsigned pkv = cp[u];
            int bin = bin0 + (u >= TLIST);
            int col = ((csq << 6) + (int)(pkv & 0x7Fu)) * 16 + bin;
            qq[u] = ((unsigned long long)pkv << 32) | (unsigned)col;
        }
        // insertion sort 10 ascending (static indices)
        #pragma unroll
        for (int i = 1; i < 10; ++i)
            #pragma unroll
            for (int jj = i; jj > 0; --jj)
                if (qq[jj] < qq[jj - 1]) {
                    unsigned long long t = qq[jj - 1];
                    qq[jj - 1] = qq[jj]; qq[jj] = t;
                }
    }

    // 16 extraction rounds of wave-wide u64 min; lane r captures round r
    unsigned long long my_sel = 0;
    #pragma unroll
    for (int round = 0; round < 16; ++round) {
        unsigned long long m = qq[0];
        #pragma unroll
        for (int off = 1; off < 64; off <<= 1) {
            unsigned long long o = __shfl_xor(m, off, 64);
            m = (o < m) ? o : m;
        }
        if (qq[0] == m) {                 // exactly one lane (u64 unique via col)
            #pragma unroll
            for (int u = 0; u < 9; ++u) qq[u] = qq[u + 1];
            qq[9] = 0xFFFFFFFFFFFFFFFFull;
        }
        if (lane == round) my_sel = m;
    }
    if (lane < 16) sel[wave][lane] = (int)((unsigned)my_sel & 0x3FFFu);
    __builtin_amdgcn_wave_barrier();

    // (b) exact f64 keys: lane = (cand c, quarter qd)
    {
        const int c = lane & 15, qd = lane >> 4;
        const int m = sel[wave][c];
        const double rdm = rdnd[bN + m];
        const float* xr = x_rm + (size_t)(bN + m) * CH + qd * 48;
        const double* xcp = &xc[wave][qd * 48];
        double s0 = 0.0, s1 = 0.0, s2 = 0.0, s3 = 0.0;
        #pragma unroll
        for (int j = 0; j < 12; ++j) {
            float4 v = *(const float4*)(xr + (j << 2));
            s0 = fma((double)v.x * rdm, xcp[(j << 2) + 0], s0);
            s1 = fma((double)v.y * rdm, xcp[(j << 2) + 1], s1);
            s2 = fma((double)v.z * rdm, xcp[(j << 2) + 2], s2);
            s3 = fma((double)v.w * rdm, xcp[(j << 2) + 3], s3);
        }
        double dot = (s0 + s1) + (s2 + s3);
        dot += __shfl_xor(dot, 16, 64);
        dot += __shfl_xor(dot, 32, 64);
        if (qd == 0) dks[wave][c] = fma(-2.0, dot, ssd[bN + m] * rdm * rdm);
    }
    __builtin_amdgcn_wave_barrier();

    // (c) 9 smallest of 16 by (key, idx) — serial on lane 0 of each wave
    if (lane == 0) {
        const int n = row;
        unsigned used = 0;
        for (int k = 0; k < KNN; ++k) {
            double bd = INFINITY; int bm = 0x7fffffff; int bp = 0;
            #pragma unroll
            for (int s = 0; s < 16; ++s) {
                if (!((used >> s) & 1u)) {
                    double d = dks[wave][s]; int m = sel[wave][s];
                    if (d < bd || (d == bd && m < bm)) { bd = d; bm = m; bp = s; }
                }
            }
            used |= (1u << bp);
            out[(size_t)(bN + n) * KNN + k] = bm;
            out[(size_t)BATCH * NPTS * KNN + (size_t)(bN + n) * KNN + k] = n;
        }
    }
}

// ---------------------------------------------------------------------------
extern "C" void kernel_launch(void* const* d_in, const int* in_sizes, int n_in,
                              void* d_out, int out_size, void* d_ws, size_t ws_size,
                              hipStream_t stream)
{
    const float* x = (const float*)d_in[0];
    int* out = (int*)d_out;

    char* ws = (char*)d_ws;
    const size_t sz_pk  = (size_t)BATCH * NTILE * KSTEP * 512 * sizeof(unsigned short); // 6.29 MB
    const size_t sz_xrm = (size_t)BATCH * NPTS * CH * sizeof(float);                    // 12.58 MB
    const size_t sz_rdn = (size_t)BATCH * NPTS * sizeof(double);
    const size_t sz_ss  = sz_rdn;

    unsigned short* pk = (unsigned short*)(ws);
    float*  x_rm   = (float*) (ws + sz_pk);
    double* rdnd   = (double*)(ws + sz_pk + sz_xrm);
    double* ssd    = (double*)(ws + sz_pk + sz_xrm + sz_rdn);
    unsigned* cand_p = (unsigned*)(ws + sz_pk + sz_xrm + sz_rdn + sz_ss);               // 41.9 MB

    knn_normalize<<<BATCH * (NPTS / NT), 256, 0, stream>>>(x, pk, x_rm, rdnd, ssd);
    knn_phase1  <<<BATCH * 64 * CSPLIT, 256, 0, stream>>>(pk, cand_p);
    knn_phase2  <<<BATCH * (NPTS / P2ROWS), 256, 0, stream>>>(x_rm, rdnd, ssd, cand_p, out);
}

// Round 11
// 182.527 us; speedup vs baseline: 1.0275x; 1.0275x over previous
//
#include <hip/hip_runtime.h>
#include <math.h>

#define BATCH 2
#define CH    192
#define NPTS  8192
#define KNN   9

#define NT     64      // rows per normalize block
#define TLIST  5       // per-bucket candidate list depth
#define NTILE  512     // 16-wide row/col tiles per batch
#define KSTEP  6       // 192 / 32
#define CSPLIT 8       // column splits (phase 1)
#define CT     2       // col tiles staged per iteration
#define NITER  ((NTILE / CSPLIT) / CT)   // 32
#define NCANDP 640     // packed candidates per row (8 cs * 16 bins * 5)
#define P2ROWS 4       // phase-2 rows per block (1 per wave)

typedef __attribute__((ext_vector_type(8))) short  bf16x8;
typedef __attribute__((ext_vector_type(8))) unsigned short u16x8;
typedef __attribute__((ext_vector_type(4))) float  f32x4;

static __device__ __forceinline__ unsigned short f2bf(float f) {
    unsigned u = __float_as_uint(f);
    u += 0x7fffu + ((u >> 16) & 1u);          // round-to-nearest-even
    return (unsigned short)(u >> 16);
}
static __device__ __forceinline__ bf16x8 negbf(bf16x8 v) {
    bf16x8 r;
    #pragma unroll
    for (int e = 0; e < 8; ++e) r[e] = (short)(v[e] ^ (short)0x8000);
    return r;
}
static __device__ __forceinline__ unsigned umax2(unsigned a, unsigned b) {
    return a > b ? a : b;
}

// ---------------------------------------------------------------------------
// Kernel A: norms + layouts (unchanged — passing since R9).
//  pk [B][tile(512)][ks(6)][lane(64)*8] bf16 hi-only MFMA-frag layout
//  x_rm [B][N][C] f32 raw; rdnd/ssd f64 per point.
// ---------------------------------------------------------------------------
__global__ __launch_bounds__(256) void knn_normalize(
    const float* __restrict__ x,
    unsigned short* __restrict__ pk, float* __restrict__ x_rm,
    double* __restrict__ rdnd, double* __restrict__ ssd)
{
    __shared__ float  tile[CH][NT + 1];
    __shared__ double rdn_sh[NT];

    const int b   = blockIdx.x >> 7;
    const int rb  = blockIdx.x & 127;
    const int n0  = rb << 6;
    const int tid = threadIdx.x;
    const float* xb = x + (size_t)b * CH * NPTS;

    #pragma unroll
    for (int i = 0; i < (CH * NT) / 256; ++i) {
        int flat = tid + i * 256;
        int c = flat >> 6, j = flat & 63;
        tile[c][j] = xb[(size_t)c * NPTS + n0 + j];
    }
    __syncthreads();

    // 4 threads per point: quarter q covers dims q*48..q*48+47
    {
        const int j = tid >> 2, q = tid & 3;
        double ss = 0.0;
        #pragma unroll 8
        for (int c = 0; c < 48; ++c) {
            double v = (double)tile[q * 48 + c][j];
            ss = fma(v, v, ss);
        }
        ss += __shfl_xor(ss, 1, 64);
        ss += __shfl_xor(ss, 2, 64);
        if (q == 0) {
            double dn = sqrt(ss);
            if (dn < 1e-12) dn = 1e-12;
            double rdn = 1.0 / dn;
            rdn_sh[j] = rdn;
            rdnd[b * NPTS + n0 + j] = rdn;
            ssd [b * NPTS + n0 + j] = ss;
        }
    }
    __syncthreads();

    // packed MFMA-frag bf16 hi (4 row-tiles * 6 ksteps = 24 frags/block)
    #pragma unroll
    for (int i = 0; i < 6; ++i) {
        int pid  = tid + i * 256;
        int frag = pid >> 6;
        int lane = pid & 63;
        int tl   = frag / KSTEP;
        int ks   = frag - tl * KSTEP;
        int rl   = (tl << 4) + (lane & 15);
        int kb   = (ks << 5) + ((lane >> 4) << 3);
        double rdn = rdn_sh[rl];
        u16x8 hv;
        #pragma unroll
        for (int e = 0; e < 8; ++e) {
            float v = (float)((double)tile[kb + e][rl] * rdn);
            hv[e] = f2bf(v);
        }
        size_t base = ((size_t)((b * NTILE + (rb << 2) + tl) * KSTEP + ks)) * 512
                      + ((size_t)lane << 3);
        *(u16x8*)(pk + base) = hv;
    }

    #pragma unroll
    for (int i = 0; i < (CH * NT) / 256; ++i) {
        int flat = tid + i * 256;
        int j = flat / CH, c = flat - j * CH;
        x_rm[(size_t)(b * NPTS + n0 + j) * CH + c] = tile[c][j];
    }
}

// ---------------------------------------------------------------------------
// Phase 1 v8: 512-thread blocks (8 waves), 1 row-tile per wave. Per-wave
// state ~77 regs -> waves_per_eu(6,6) = 3 blocks/CU = 6 waves/SIMD TLP
// (R10 postmortem: 2.7 effective waves/SIMD exposed barrier-drain + dep
// stalls). Staging bytes halve (8 waves share each 12 KB B-tile). Keys per
// wave-iter halve to 8. Candidate format unchanged.
// ---------------------------------------------------------------------------
__global__ __attribute__((amdgpu_flat_work_group_size(512, 512),
                          amdgpu_waves_per_eu(6, 6)))
void knn_phase1(
    const unsigned short* __restrict__ pk,
    unsigned* __restrict__ cand_p)
{
    __shared__ unsigned short ldsB[2][CT * KSTEP * 512];   // 2 x 12288 B

    const int bid  = blockIdx.x;          // 1024
    const int b    = bid >> 9;
    const int r9   = bid & 511;
    const int rb   = r9 >> 3;             // row block (128 rows), 0..63
    const int cs   = r9 & 7;              // column split, 0..7
    const int tid  = threadIdx.x;
    const int wave = tid >> 6;            // 0..7
    const int lane = tid & 63;
    const unsigned short* pkb = pk + (size_t)b * (NTILE * KSTEP * 512);
    const int ct0 = cs * (NTILE / CSPLIT);       // 64 tiles per split

    // A fragments: 1 row tile per wave, NEGATED (for acc = 4 - inner)
    const int rt = rb * 8 + wave;
    bf16x8 a_hi[KSTEP];
    #pragma unroll
    for (int ks = 0; ks < KSTEP; ++ks) {
        const unsigned short* p = pkb + ((size_t)(rt * KSTEP + ks)) * 512 + (lane << 3);
        a_hi[ks] = negbf(*(const bf16x8*)p);
    }
    #pragma unroll
    for (int ks = 0; ks < KSTEP; ++ks)
        asm volatile("" : "+a"(a_hi[ks]));   // MFMA-only operand: AGPR class

    // packed lists; sentinels above all real keys (real < 0x40C00000)
    unsigned lst[4][TLIST];
    unsigned wmax[4];
    #pragma unroll
    for (int s = 0; s < 4; ++s) {
        #pragma unroll
        for (int t = 0; t < TLIST; ++t) lst[s][t] = 0xFFFFFF00u | t;
        wmax[s] = 0xFFFFFF00u | (TLIST - 1);
    }

    // prologue stage of buffer 0 (12 KB = 3 x 256 x 16B, waves 0-3 issue)
    if (tid < 256) {
        const char* g = (const char*)(pkb + (size_t)ct0 * (KSTEP * 512));
        #pragma unroll
        for (int k = 0; k < 3; ++k) {
            int off = (k * 256 + tid) * 16;
            __builtin_amdgcn_global_load_lds(
                (const __attribute__((address_space(1))) unsigned int*)(g + off),
                (__attribute__((address_space(3))) unsigned int*)((char*)&ldsB[0][0] + off),
                16, 0, 0);
        }
    }
    __syncthreads();

    for (int it = 0; it < NITER; ++it) {
        const int cur = it & 1;
        if (it + 1 < NITER && tid < 256) {
            const char* g = (const char*)(pkb + (size_t)(ct0 + (it + 1) * CT) * (KSTEP * 512));
            #pragma unroll
            for (int k = 0; k < 3; ++k) {
                int off = (k * 256 + tid) * 16;
                __builtin_amdgcn_global_load_lds(
                    (const __attribute__((address_space(1))) unsigned int*)(g + off),
                    (__attribute__((address_space(3))) unsigned int*)((char*)&ldsB[cur ^ 1][0] + off),
                    16, 0, 0);
            }
        }

        f32x4 acc[CT];
        #pragma unroll
        for (int j = 0; j < CT; ++j) acc[j] = (f32x4){4.f, 4.f, 4.f, 4.f};

        #pragma unroll
        for (int ks = 0; ks < KSTEP; ++ks) {
            #pragma unroll
            for (int j = 0; j < CT; ++j) {
                bf16x8 bh = *(const bf16x8*)&ldsB[cur][(j * KSTEP + ks) * 512 + (lane << 3)];
                acc[j] = __builtin_amdgcn_mfma_f32_16x16x32_bf16(a_hi[ks], bh, acc[j], 0, 0, 0);
            }
        }

        // selection: key = 4 - inner (positive) -> p = (bits & ~0x7F) | tile
        #pragma unroll
        for (int j = 0; j < CT; ++j) {
            const unsigned ctl = (unsigned)(it * CT + j);   // 0..63
            #pragma unroll
            for (int s = 0; s < 4; ++s) {
                unsigned p = (__float_as_uint(acc[j][s]) & 0xFFFFFF80u) | ctl;
                const unsigned wm = wmax[s];
                if (p < wm) {
                    #pragma unroll
                    for (int t = 0; t < TLIST; ++t)
                        lst[s][t] = (lst[s][t] == wm) ? p : lst[s][t];
                    unsigned m0 = umax2(umax2(lst[s][0], lst[s][1]), lst[s][2]);
                    wmax[s] = umax2(umax2(m0, lst[s][3]), lst[s][4]);
                }
            }
        }
        __syncthreads();
    }

    // write candidates: [B*N][640], slot = cs*80 + bin*5 + t
    const int bin = lane & 15;
    #pragma unroll
    for (int s = 0; s < 4; ++s) {
        int row = (rt << 4) + ((lane >> 4) << 2) + s;
        size_t base = (size_t)(b * NPTS + row) * NCANDP + cs * 80 + bin * 5;
        #pragma unroll
        for (int t = 0; t < TLIST; ++t)
            cand_p[base + t] = lst[s][t];
    }
}

// ---------------------------------------------------------------------------
// Phase 2 (unchanged from R8 — passing): 1 row per wave, 4 rows/block.
//  (a) per-lane 10 packed cands (2 buckets of 5), insertion-sort, 16-round
//      wave-min extraction
//  (b) f64 re-rank: lane=(cand,quarter), float4 gathers, 2-shfl reduce
//  (c) lane-0 serial 9-of-16 by (f64 key, idx)
// ---------------------------------------------------------------------------
__global__ __launch_bounds__(256) void knn_phase2(
    const float* __restrict__ x_rm,
    const double* __restrict__ rdnd, const double* __restrict__ ssd,
    const unsigned* __restrict__ cand_p,
    int* __restrict__ out)
{
    __shared__ double xc[P2ROWS][CH];     // 6144 B
    __shared__ int    sel[P2ROWS][16];
    __shared__ double dks[P2ROWS][16];

    const int bi   = blockIdx.x;          // 4096
    const int b    = bi >> 11;
    const int r0   = (bi & 2047) << 2;
    const int tid  = threadIdx.x;
    const int wave = tid >> 6;
    const int lane = tid & 63;
    const int bN   = b * NPTS;

    for (int i = tid; i < P2ROWS * CH; i += 256) {
        int r = i / CH, c = i - r * CH;
        xc[r][c] = (double)x_rm[(size_t)(bN + r0 + r) * CH + c] * rdnd[bN + r0 + r];
    }
    __syncthreads();

    const int row = r0 + wave;

    // (a) lane's 10 slots: cs = lane>>3; bins (lane&7)*2 + u/5
    unsigned long long qq[10];
    {
        const unsigned* cp = cand_p + (size_t)(bN + row) * NCANDP + lane * 10;
        const int csq = lane >> 3;
        const int bin0 = (lane & 7) << 1;
        #pragma unroll
        for (int u = 0; u < 10; ++u) {
            unsigned pkv = cp[u];
            int bin = bin0 + (u >= TLIST);
            int col = ((csq << 6) + (int)(pkv & 0x7Fu)) * 16 + bin;
            qq[u] = ((unsigned long long)pkv << 32) | (unsigned)col;
        }
        // insertion sort 10 ascending (static indices)
        #pragma unroll
        for (int i = 1; i < 10; ++i)
            #pragma unroll
            for (int jj = i; jj > 0; --jj)
                if (qq[jj] < qq[jj - 1]) {
                    unsigned long long t = qq[jj - 1];
                    qq[jj - 1] = qq[jj]; qq[jj] = t;
                }
    }

    // 16 extraction rounds of wave-wide u64 min; lane r captures round r
    unsigned long long my_sel = 0;
    #pragma unroll
    for (int round = 0; round < 16; ++round) {
        unsigned long long m = qq[0];
        #pragma unroll
        for (int off = 1; off < 64; off <<= 1) {
            unsigned long long o = __shfl_xor(m, off, 64);
            m = (o < m) ? o : m;
        }
        if (qq[0] == m) {                 // exactly one lane (u64 unique via col)
            #pragma unroll
            for (int u = 0; u < 9; ++u) qq[u] = qq[u + 1];
            qq[9] = 0xFFFFFFFFFFFFFFFFull;
        }
        if (lane == round) my_sel = m;
    }
    if (lane < 16) sel[wave][lane] = (int)((unsigned)my_sel & 0x3FFFu);
    __builtin_amdgcn_wave_barrier();

    // (b) exact f64 keys: lane = (cand c, quarter qd)
    {
        const int c = lane & 15, qd = lane >> 4;
        const int m = sel[wave][c];
        const double rdm = rdnd[bN + m];
        const float* xr = x_rm + (size_t)(bN + m) * CH + qd * 48;
        const double* xcp = &xc[wave][qd * 48];
        double s0 = 0.0, s1 = 0.0, s2 = 0.0, s3 = 0.0;
        #pragma unroll
        for (int j = 0; j < 12; ++j) {
            float4 v = *(const float4*)(xr + (j << 2));
            s0 = fma((double)v.x * rdm, xcp[(j << 2) + 0], s0);
            s1 = fma((double)v.y * rdm, xcp[(j << 2) + 1], s1);
            s2 = fma((double)v.z * rdm, xcp[(j << 2) + 2], s2);
            s3 = fma((double)v.w * rdm, xcp[(j << 2) + 3], s3);
        }
        double dot = (s0 + s1) + (s2 + s3);
        dot += __shfl_xor(dot, 16, 64);
        dot += __shfl_xor(dot, 32, 64);
        if (qd == 0) dks[wave][c] = fma(-2.0, dot, ssd[bN + m] * rdm * rdm);
    }
    __builtin_amdgcn_wave_barrier();

    // (c) 9 smallest of 16 by (key, idx) — serial on lane 0 of each wave
    if (lane == 0) {
        const int n = row;
        unsigned used = 0;
        for (int k = 0; k < KNN; ++k) {
            double bd = INFINITY; int bm = 0x7fffffff; int bp = 0;
            #pragma unroll
            for (int s = 0; s < 16; ++s) {
                if (!((used >> s) & 1u)) {
                    double d = dks[wave][s]; int m = sel[wave][s];
                    if (d < bd || (d == bd && m < bm)) { bd = d; bm = m; bp = s; }
                }
            }
            used |= (1u << bp);
            out[(size_t)(bN + n) * KNN + k] = bm;
            out[(size_t)BATCH * NPTS * KNN + (size_t)(bN + n) * KNN + k] = n;
        }
    }
}

// ---------------------------------------------------------------------------
extern "C" void kernel_launch(void* const* d_in, const int* in_sizes, int n_in,
                              void* d_out, int out_size, void* d_ws, size_t ws_size,
                              hipStream_t stream)
{
    const float* x = (const float*)d_in[0];
    int* out = (int*)d_out;

    char* ws = (char*)d_ws;
    const size_t sz_pk  = (size_t)BATCH * NTILE * KSTEP * 512 * sizeof(unsigned short); // 6.29 MB
    const size_t sz_xrm = (size_t)BATCH * NPTS * CH * sizeof(float);                    // 12.58 MB
    const size_t sz_rdn = (size_t)BATCH * NPTS * sizeof(double);
    const size_t sz_ss  = sz_rdn;

    unsigned short* pk = (unsigned short*)(ws);
    float*  x_rm   = (float*) (ws + sz_pk);
    double* rdnd   = (double*)(ws + sz_pk + sz_xrm);
    double* ssd    = (double*)(ws + sz_pk + sz_xrm + sz_rdn);
    unsigned* cand_p = (unsigned*)(ws + sz_pk + sz_xrm + sz_rdn + sz_ss);               // 41.9 MB

    knn_normalize<<<BATCH * (NPTS / NT), 256, 0, stream>>>(x, pk, x_rm, rdnd, ssd);
    knn_phase1  <<<BATCH * 64 * CSPLIT, 512, 0, stream>>>(pk, cand_p);
    knn_phase2  <<<BATCH * (NPTS / P2ROWS), 256, 0, stream>>>(x_rm, rdnd, ssd, cand_p, out);
}

// Round 12
// 157.675 us; speedup vs baseline: 1.1894x; 1.1576x over previous
//
#include <hip/hip_runtime.h>
#include <math.h>

#define BATCH 2
#define CH    192
#define NPTS  8192
#define KNN   9

#define NT     64      // rows per normalize block
#define TLIST  5       // per-bucket candidate list depth
#define NTILE  512     // 16-wide row/col tiles per batch
#define KSTEP  6       // 192 / 32
#define CSPLIT 8       // column splits (phase 1)
#define CT     2       // col tiles staged per iteration
#define NITER  ((NTILE / CSPLIT) / CT)   // 32
#define NCANDP 640     // packed candidates per row (8 cs * 16 bins * 5)
#define P2ROWS 4       // phase-2 rows per block (1 per wave)
#define NSEL   12      // candidates exactly re-ranked per row

typedef __attribute__((ext_vector_type(8))) short  bf16x8;
typedef __attribute__((ext_vector_type(8))) unsigned short u16x8;
typedef __attribute__((ext_vector_type(4))) float  f32x4;

static __device__ __forceinline__ unsigned short f2bf(float f) {
    unsigned u = __float_as_uint(f);
    u += 0x7fffu + ((u >> 16) & 1u);          // round-to-nearest-even
    return (unsigned short)(u >> 16);
}
static __device__ __forceinline__ bf16x8 negbf(bf16x8 v) {
    bf16x8 r;
    #pragma unroll
    for (int e = 0; e < 8; ++e) r[e] = (short)(v[e] ^ (short)0x8000);
    return r;
}
static __device__ __forceinline__ unsigned umax2(unsigned a, unsigned b) {
    return a > b ? a : b;
}

// ---------------------------------------------------------------------------
// Kernel A: norms + layouts (unchanged — passing since R9).
//  pk [B][tile(512)][ks(6)][lane(64)*8] bf16 hi-only MFMA-frag layout
//  x_rm [B][N][C] f32 raw; rdnd/ssd f64 per point.
// ---------------------------------------------------------------------------
__global__ __launch_bounds__(256) void knn_normalize(
    const float* __restrict__ x,
    unsigned short* __restrict__ pk, float* __restrict__ x_rm,
    double* __restrict__ rdnd, double* __restrict__ ssd)
{
    __shared__ float  tile[CH][NT + 1];
    __shared__ double rdn_sh[NT];

    const int b   = blockIdx.x >> 7;
    const int rb  = blockIdx.x & 127;
    const int n0  = rb << 6;
    const int tid = threadIdx.x;
    const float* xb = x + (size_t)b * CH * NPTS;

    #pragma unroll
    for (int i = 0; i < (CH * NT) / 256; ++i) {
        int flat = tid + i * 256;
        int c = flat >> 6, j = flat & 63;
        tile[c][j] = xb[(size_t)c * NPTS + n0 + j];
    }
    __syncthreads();

    // 4 threads per point: quarter q covers dims q*48..q*48+47
    {
        const int j = tid >> 2, q = tid & 3;
        double ss = 0.0;
        #pragma unroll 8
        for (int c = 0; c < 48; ++c) {
            double v = (double)tile[q * 48 + c][j];
            ss = fma(v, v, ss);
        }
        ss += __shfl_xor(ss, 1, 64);
        ss += __shfl_xor(ss, 2, 64);
        if (q == 0) {
            double dn = sqrt(ss);
            if (dn < 1e-12) dn = 1e-12;
            double rdn = 1.0 / dn;
            rdn_sh[j] = rdn;
            rdnd[b * NPTS + n0 + j] = rdn;
            ssd [b * NPTS + n0 + j] = ss;
        }
    }
    __syncthreads();

    // packed MFMA-frag bf16 hi (4 row-tiles * 6 ksteps = 24 frags/block)
    #pragma unroll
    for (int i = 0; i < 6; ++i) {
        int pid  = tid + i * 256;
        int frag = pid >> 6;
        int lane = pid & 63;
        int tl   = frag / KSTEP;
        int ks   = frag - tl * KSTEP;
        int rl   = (tl << 4) + (lane & 15);
        int kb   = (ks << 5) + ((lane >> 4) << 3);
        double rdn = rdn_sh[rl];
        u16x8 hv;
        #pragma unroll
        for (int e = 0; e < 8; ++e) {
            float v = (float)((double)tile[kb + e][rl] * rdn);
            hv[e] = f2bf(v);
        }
        size_t base = ((size_t)((b * NTILE + (rb << 2) + tl) * KSTEP + ks)) * 512
                      + ((size_t)lane << 3);
        *(u16x8*)(pk + base) = hv;
    }

    #pragma unroll
    for (int i = 0; i < (CH * NT) / 256; ++i) {
        int flat = tid + i * 256;
        int j = flat / CH, c = flat - j * CH;
        x_rm[(size_t)(b * NPTS + n0 + j) * CH + c] = tile[c][j];
    }
}

// ---------------------------------------------------------------------------
// Phase 1 v9: R11 structure (512-thr blocks, 1 row-tile/wave) but
// waves_per_eu(4,4): unified budget 128/wave so lst/wmax (24 regs) fit the
// ARCH class (R11's (6,6)=85 split 40 arch + 45 agpr -> lists in AGPR ->
// ~12 accvgpr moves per key = the measured 306-vs-200 instr gap). Measured
// occupancy was ~4 waves/SIMD anyway, so no TLP loss.
// ---------------------------------------------------------------------------
__global__ __attribute__((amdgpu_flat_work_group_size(512, 512),
                          amdgpu_waves_per_eu(4, 4)))
void knn_phase1(
    const unsigned short* __restrict__ pk,
    unsigned* __restrict__ cand_p)
{
    __shared__ unsigned short ldsB[2][CT * KSTEP * 512];   // 2 x 12288 B

    const int bid  = blockIdx.x;          // 1024
    const int b    = bid >> 9;
    const int r9   = bid & 511;
    const int rb   = r9 >> 3;             // row block (128 rows), 0..63
    const int cs   = r9 & 7;              // column split, 0..7
    const int tid  = threadIdx.x;
    const int wave = tid >> 6;            // 0..7
    const int lane = tid & 63;
    const unsigned short* pkb = pk + (size_t)b * (NTILE * KSTEP * 512);
    const int ct0 = cs * (NTILE / CSPLIT);       // 64 tiles per split

    // A fragments: 1 row tile per wave, NEGATED (for acc = 4 - inner)
    const int rt = rb * 8 + wave;
    bf16x8 a_hi[KSTEP];
    #pragma unroll
    for (int ks = 0; ks < KSTEP; ++ks) {
        const unsigned short* p = pkb + ((size_t)(rt * KSTEP + ks)) * 512 + (lane << 3);
        a_hi[ks] = negbf(*(const bf16x8*)p);
    }
    #pragma unroll
    for (int ks = 0; ks < KSTEP; ++ks)
        asm volatile("" : "+a"(a_hi[ks]));   // MFMA-only operand: AGPR class

    // packed lists; sentinels above all real keys (real < 0x40C00000)
    unsigned lst[4][TLIST];
    unsigned wmax[4];
    #pragma unroll
    for (int s = 0; s < 4; ++s) {
        #pragma unroll
        for (int t = 0; t < TLIST; ++t) lst[s][t] = 0xFFFFFF00u | t;
        wmax[s] = 0xFFFFFF00u | (TLIST - 1);
    }

    // prologue stage of buffer 0 (12 KB = 3 x 256 x 16B, waves 0-3 issue)
    if (tid < 256) {
        const char* g = (const char*)(pkb + (size_t)ct0 * (KSTEP * 512));
        #pragma unroll
        for (int k = 0; k < 3; ++k) {
            int off = (k * 256 + tid) * 16;
            __builtin_amdgcn_global_load_lds(
                (const __attribute__((address_space(1))) unsigned int*)(g + off),
                (__attribute__((address_space(3))) unsigned int*)((char*)&ldsB[0][0] + off),
                16, 0, 0);
        }
    }
    __syncthreads();

    for (int it = 0; it < NITER; ++it) {
        const int cur = it & 1;
        if (it + 1 < NITER && tid < 256) {
            const char* g = (const char*)(pkb + (size_t)(ct0 + (it + 1) * CT) * (KSTEP * 512));
            #pragma unroll
            for (int k = 0; k < 3; ++k) {
                int off = (k * 256 + tid) * 16;
                __builtin_amdgcn_global_load_lds(
                    (const __attribute__((address_space(1))) unsigned int*)(g + off),
                    (__attribute__((address_space(3))) unsigned int*)((char*)&ldsB[cur ^ 1][0] + off),
                    16, 0, 0);
            }
        }

        f32x4 acc[CT];
        #pragma unroll
        for (int j = 0; j < CT; ++j) acc[j] = (f32x4){4.f, 4.f, 4.f, 4.f};

        #pragma unroll
        for (int ks = 0; ks < KSTEP; ++ks) {
            #pragma unroll
            for (int j = 0; j < CT; ++j) {
                bf16x8 bh = *(const bf16x8*)&ldsB[cur][(j * KSTEP + ks) * 512 + (lane << 3)];
                acc[j] = __builtin_amdgcn_mfma_f32_16x16x32_bf16(a_hi[ks], bh, acc[j], 0, 0, 0);
            }
        }

        // selection: key = 4 - inner (positive) -> p = (bits & ~0x7F) | tile
        #pragma unroll
        for (int j = 0; j < CT; ++j) {
            const unsigned ctl = (unsigned)(it * CT + j);   // 0..63
            #pragma unroll
            for (int s = 0; s < 4; ++s) {
                unsigned p = (__float_as_uint(acc[j][s]) & 0xFFFFFF80u) | ctl;
                const unsigned wm = wmax[s];
                if (p < wm) {
                    #pragma unroll
                    for (int t = 0; t < TLIST; ++t)
                        lst[s][t] = (lst[s][t] == wm) ? p : lst[s][t];
                    unsigned m0 = umax2(umax2(lst[s][0], lst[s][1]), lst[s][2]);
                    wmax[s] = umax2(umax2(m0, lst[s][3]), lst[s][4]);
                }
            }
        }
        __syncthreads();
    }

    // write candidates: [B*N][640], slot = cs*80 + bin*5 + t
    const int bin = lane & 15;
    #pragma unroll
    for (int s = 0; s < 4; ++s) {
        int row = (rt << 4) + ((lane >> 4) << 2) + s;
        size_t base = (size_t)(b * NPTS + row) * NCANDP + cs * 80 + bin * 5;
        #pragma unroll
        for (int t = 0; t < TLIST; ++t)
            cand_p[base + t] = lst[s][t];
    }
}

// ---------------------------------------------------------------------------
// Phase 2: 1 row per wave, 4 rows/block, 4096 blocks.
//  (a) per-lane 10 packed cands (2 buckets of 5), insertion-sort, NSEL(12)-
//      round wave-min extraction
//  (b) f64 re-rank (12 cands): lane=(cand,quarter), float4 gathers, 2-shfl
//  (c) lane-0 serial 9-of-12 by (f64 key, idx)
// ---------------------------------------------------------------------------
__global__ __launch_bounds__(256) void knn_phase2(
    const float* __restrict__ x_rm,
    const double* __restrict__ rdnd, const double* __restrict__ ssd,
    const unsigned* __restrict__ cand_p,
    int* __restrict__ out)
{
    __shared__ double xc[P2ROWS][CH];     // 6144 B
    __shared__ int    sel[P2ROWS][16];
    __shared__ double dks[P2ROWS][16];

    const int bi   = blockIdx.x;          // 4096
    const int b    = bi >> 11;
    const int r0   = (bi & 2047) << 2;
    const int tid  = threadIdx.x;
    const int wave = tid >> 6;
    const int lane = tid & 63;
    const int bN   = b * NPTS;

    for (int i = tid; i < P2ROWS * CH; i += 256) {
        int r = i / CH, c = i - r * CH;
        xc[r][c] = (double)x_rm[(size_t)(bN + r0 + r) * CH + c] * rdnd[bN + r0 + r];
    }
    __syncthreads();

    const int row = r0 + wave;

    // (a) lane's 10 slots: cs = lane>>3; bins (lane&7)*2 + u/5
    unsigned long long qq[10];
    {
        const unsigned* cp = cand_p + (size_t)(bN + row) * NCANDP + lane * 10;
        const int csq = lane >> 3;
        const int bin0 = (lane & 7) << 1;
        #pragma unroll
        for (int u = 0; u < 10; ++u) {
            unsigned pkv = cp[u];
            int bin = bin0 + (u >= TLIST);
            int col = ((csq << 6) + (int)(pkv & 0x7Fu)) * 16 + bin;
            qq[u] = ((unsigned long long)pkv << 32) | (unsigned)col;
        }
        // insertion sort 10 ascending (static indices)
        #pragma unroll
        for (int i = 1; i < 10; ++i)
            #pragma unroll
            for (int jj = i; jj > 0; --jj)
                if (qq[jj] < qq[jj - 1]) {
                    unsigned long long t = qq[jj - 1];
                    qq[jj - 1] = qq[jj]; qq[jj] = t;
                }
    }

    // NSEL extraction rounds of wave-wide u64 min; lane r captures round r
    unsigned long long my_sel = 0;
    #pragma unroll
    for (int round = 0; round < NSEL; ++round) {
        unsigned long long m = qq[0];
        #pragma unroll
        for (int off = 1; off < 64; off <<= 1) {
            unsigned long long o = __shfl_xor(m, off, 64);
            m = (o < m) ? o : m;
        }
        if (qq[0] == m) {                 // exactly one lane (u64 unique via col)
            #pragma unroll
            for (int u = 0; u < 9; ++u) qq[u] = qq[u + 1];
            qq[9] = 0xFFFFFFFFFFFFFFFFull;
        }
        if (lane == round) my_sel = m;
    }
    if (lane < NSEL) sel[wave][lane] = (int)((unsigned)my_sel & 0x3FFFu);
    __builtin_amdgcn_wave_barrier();

    // (b) exact f64 keys: lane = (cand c, quarter qd), c < NSEL active
    {
        const int c = lane & 15, qd = lane >> 4;
        if (c < NSEL) {
            const int m = sel[wave][c];
            const double rdm = rdnd[bN + m];
            const float* xr = x_rm + (size_t)(bN + m) * CH + qd * 48;
            const double* xcp = &xc[wave][qd * 48];
            double s0 = 0.0, s1 = 0.0, s2 = 0.0, s3 = 0.0;
            #pragma unroll
            for (int j = 0; j < 12; ++j) {
                float4 v = *(const float4*)(xr + (j << 2));
                s0 = fma((double)v.x * rdm, xcp[(j << 2) + 0], s0);
                s1 = fma((double)v.y * rdm, xcp[(j << 2) + 1], s1);
                s2 = fma((double)v.z * rdm, xcp[(j << 2) + 2], s2);
                s3 = fma((double)v.w * rdm, xcp[(j << 2) + 3], s3);
            }
            double dot = (s0 + s1) + (s2 + s3);
            dot += __shfl_xor(dot, 16, 64);
            dot += __shfl_xor(dot, 32, 64);
            if (qd == 0) dks[wave][c] = fma(-2.0, dot, ssd[bN + m] * rdm * rdm);
        } else {
            // keep shuffles wave-uniform: lanes c>=NSEL still participate
            double dot = 0.0;
            dot += __shfl_xor(dot, 16, 64);
            dot += __shfl_xor(dot, 32, 64);
        }
    }
    __builtin_amdgcn_wave_barrier();

    // (c) 9 smallest of NSEL by (key, idx) — serial on lane 0 of each wave
    if (lane == 0) {
        const int n = row;
        unsigned used = 0;
        for (int k = 0; k < KNN; ++k) {
            double bd = INFINITY; int bm = 0x7fffffff; int bp = 0;
            #pragma unroll
            for (int s = 0; s < NSEL; ++s) {
                if (!((used >> s) & 1u)) {
                    double d = dks[wave][s]; int m = sel[wave][s];
                    if (d < bd || (d == bd && m < bm)) { bd = d; bm = m; bp = s; }
                }
            }
            used |= (1u << bp);
            out[(size_t)(bN + n) * KNN + k] = bm;
            out[(size_t)BATCH * NPTS * KNN + (size_t)(bN + n) * KNN + k] = n;
        }
    }
}

// ---------------------------------------------------------------------------
extern "C" void kernel_launch(void* const* d_in, const int* in_sizes, int n_in,
                              void* d_out, int out_size, void* d_ws, size_t ws_size,
                              hipStream_t stream)
{
    const float* x = (const float*)d_in[0];
    int* out = (int*)d_out;

    char* ws = (char*)d_ws;
    const size_t sz_pk  = (size_t)BATCH * NTILE * KSTEP * 512 * sizeof(unsigned short); // 6.29 MB
    const size_t sz_xrm = (size_t)BATCH * NPTS * CH * sizeof(float);                    // 12.58 MB
    const size_t sz_rdn = (size_t)BATCH * NPTS * sizeof(double);
    const size_t sz_ss  = sz_rdn;

    unsigned short* pk = (unsigned short*)(ws);
    float*  x_rm   = (float*) (ws + sz_pk);
    double* rdnd   = (double*)(ws + sz_pk + sz_xrm);
    double* ssd    = (double*)(ws + sz_pk + sz_xrm + sz_rdn);
    unsigned* cand_p = (unsigned*)(ws + sz_pk + sz_xrm + sz_rdn + sz_ss);               // 41.9 MB

    knn_normalize<<<BATCH * (NPTS / NT), 256, 0, stream>>>(x, pk, x_rm, rdnd, ssd);
    knn_phase1  <<<BATCH * 64 * CSPLIT, 512, 0, stream>>>(pk, cand_p);
    knn_phase2  <<<BATCH * (NPTS / P2ROWS), 256, 0, stream>>>(x_rm, rdnd, ssd, cand_p, out);
}